// Round 10
// baseline (1889.769 us; speedup 1.0000x reference)
//
#include <hip/hip_runtime.h>
#include <hip/hip_bf16.h>

#define NNODES 50000
#define TSTEPS 8
#define NEDGES 800000
#define VVOCAB 1000
#define DDIM 32
#define HDIM 128
#define G0DIM 64
#define H3 384
#define NCH 98  // ceil(NNODES/512) chunks per timestep

typedef _Float16 v8h __attribute__((ext_vector_type(8)));
typedef float v4f __attribute__((ext_vector_type(4)));

// ---------------- zero fill for int counters ---------------------------------------------
__global__ __launch_bounds__(256) void fill_zero_int(int* __restrict__ p, int n) {
  int i = blockIdx.x * 256 + threadIdx.x;
  if (i < n) p[i] = 0;
}

// ---------------- batched histogram + rank capture (the ONLY global atomics) --------------
__global__ __launch_bounds__(256) void hist_all(const int* __restrict__ edges,
                                                int* __restrict__ deg,
                                                int* __restrict__ rank) {
  int e = blockIdx.x * 256 + threadIdx.x;
  int t = blockIdx.y;
  if (e >= NEDGES) return;
  int dst = edges[(size_t)t * 2 * NEDGES + NEDGES + e];
  rank[(size_t)t * NEDGES + e] = atomicAdd(&deg[t * NNODES + dst], 1);
}

// ---------------- hierarchical scan: K1 chunk sums ----------------------------------------
__global__ __launch_bounds__(256) void scan_k1(const int* __restrict__ deg,
                                               int* __restrict__ csum) {
  int bid = blockIdx.x;  // t*NCH + c
  int t = bid / NCH, c = bid % NCH;
  int tid = threadIdx.x;
  int s = 0;
#pragma unroll
  for (int i = 0; i < 2; ++i) {
    int n = c * 512 + tid + i * 256;
    if (n < NNODES) s += deg[t * NNODES + n];
  }
#pragma unroll
  for (int off = 32; off > 0; off >>= 1) s += __shfl_down(s, off, 64);
  __shared__ int wsum[4];
  if ((tid & 63) == 0) wsum[tid >> 6] = s;
  __syncthreads();
  if (tid == 0) csum[bid] = wsum[0] + wsum[1] + wsum[2] + wsum[3];
}

// ---------------- K2: per-t exclusive scan of 98 chunk sums -------------------------------
__global__ __launch_bounds__(128) void scan_k2(const int* __restrict__ csum,
                                               int* __restrict__ cbase,
                                               int* __restrict__ off) {
  int t = blockIdx.x;
  int tid = threadIdx.x;
  __shared__ int buf[128];
  int own = (tid < NCH) ? csum[t * NCH + tid] : 0;
  buf[tid] = own;
  __syncthreads();
  for (int d = 1; d < 128; d <<= 1) {
    int v = (tid >= d) ? buf[tid - d] : 0;
    __syncthreads();
    buf[tid] += v;
    __syncthreads();
  }
  if (tid < NCH) cbase[t * NCH + tid] = buf[tid] - own;
  if (tid == 0) off[(size_t)t * (NNODES + 1) + NNODES] = NEDGES;
}

// ---------------- K3: in-chunk exclusive scan + base -> off -------------------------------
__global__ __launch_bounds__(512) void scan_k3(const int* __restrict__ deg,
                                               const int* __restrict__ cbase,
                                               int* __restrict__ off) {
  int bid = blockIdx.x;
  int t = bid / NCH, c = bid % NCH;
  int tid = threadIdx.x;
  int n = c * 512 + tid;
  int d = (n < NNODES) ? deg[t * NNODES + n] : 0;
  __shared__ int buf[512];
  buf[tid] = d;
  __syncthreads();
  for (int s = 1; s < 512; s <<= 1) {
    int v = (tid >= s) ? buf[tid - s] : 0;
    __syncthreads();
    buf[tid] += v;
    __syncthreads();
  }
  if (n < NNODES) {
    off[(size_t)t * (NNODES + 1) + n] = cbase[bid] + buf[tid] - d;
  }
}

// ---------------- CSR fill, ALL timesteps, atomic-free (pos = off[dst] + rank) ------------
__global__ __launch_bounds__(256) void fill_csr_all(
    const int* __restrict__ edges, const float* __restrict__ weights,
    const int* __restrict__ rank, const int* __restrict__ offs,
    int2* __restrict__ csr) {
  int e = blockIdx.x * 256 + threadIdx.x;
  int t = blockIdx.y;
  if (e >= NEDGES) return;
  const int* eb = edges + (size_t)t * 2 * NEDGES;
  int dst = eb[NEDGES + e];
  int pos = offs[(size_t)t * (NNODES + 1) + dst] + rank[(size_t)t * NEDGES + e];
  int2 pk;
  pk.x = eb[e];
  pk.y = __float_as_int(weights[(size_t)t * NEDGES + e]);
  csr[(size_t)t * NEDGES + pos] = pk;
}

// ---------------- pull aggregation fp16, 4-edge-unrolled ILP ------------------------------
template <int D>
__global__ __launch_bounds__(256) void gather_agg_h(
    const int* __restrict__ off, const int2* __restrict__ csr,
    const _Float16* __restrict__ x, _Float16* __restrict__ m) {
  const int LPN = D / 8;
  int n = blockIdx.x * (256 / LPN) + threadIdx.x / LPN;
  int l = threadIdx.x % LPN;
  if (n >= NNODES) return;
  int s0 = off[n], s1 = off[n + 1];
  float a0[8], a1[8], a2[8], a3[8];
#pragma unroll
  for (int i = 0; i < 8; ++i) { a0[i] = 0.f; a1[i] = 0.f; a2[i] = 0.f; a3[i] = 0.f; }
  int e = s0;
  for (; e + 3 < s1; e += 4) {
    int2 e0 = csr[e], e1 = csr[e + 1], e2 = csr[e + 2], e3 = csr[e + 3];
    v8h x0 = *(const v8h*)&x[(size_t)e0.x * D + l * 8];
    v8h x1 = *(const v8h*)&x[(size_t)e1.x * D + l * 8];
    v8h x2 = *(const v8h*)&x[(size_t)e2.x * D + l * 8];
    v8h x3 = *(const v8h*)&x[(size_t)e3.x * D + l * 8];
    float w0 = __int_as_float(e0.y), w1 = __int_as_float(e1.y);
    float w2 = __int_as_float(e2.y), w3 = __int_as_float(e3.y);
#pragma unroll
    for (int i = 0; i < 8; ++i) {
      a0[i] += w0 * (float)x0[i];
      a1[i] += w1 * (float)x1[i];
      a2[i] += w2 * (float)x2[i];
      a3[i] += w3 * (float)x3[i];
    }
  }
  for (; e < s1; ++e) {
    int2 eA = csr[e];
    v8h xA = *(const v8h*)&x[(size_t)eA.x * D + l * 8];
    float wA = __int_as_float(eA.y);
#pragma unroll
    for (int i = 0; i < 8; ++i) a0[i] += wA * (float)xA[i];
  }
  v8h r;
#pragma unroll
  for (int i = 0; i < 8; ++i) r[i] = (_Float16)((a0[i] + a1[i]) + (a2[i] + a3[i]));
  *(v8h*)&m[(size_t)n * D + l * 8] = r;
}

// ---- fused weight precompute: Wf32[t] = W2_t @ Wx ([128,128]@[128,384]) ------------------
__global__ __launch_bounds__(384) void fuse_w(
    const float* __restrict__ gW2, const float* __restrict__ Wx, float* __restrict__ Wf) {
  int t = blockIdx.x >> 7;
  int k = blockIdx.x & 127;
  int j = threadIdx.x;
  __shared__ float row[HDIM];
  if (j < HDIM) row[j] = gW2[((size_t)t * HDIM + k) * HDIM + j];
  __syncthreads();
  float acc = 0.f;
#pragma unroll 8
  for (int c = 0; c < HDIM; ++c) acc += row[c] * Wx[c * H3 + j];
  Wf[((size_t)t * HDIM + k) * H3 + j] = acc;
}

// ---- fused bias precompute: bf[t] = b2_t @ Wx + bx ---------------------------------------
__global__ __launch_bounds__(384) void fuse_b(
    const float* __restrict__ gb2, const float* __restrict__ Wx,
    const float* __restrict__ bx, float* __restrict__ bf) {
  int t = blockIdx.x;
  int j = threadIdx.x;
  __shared__ float row[HDIM];
  if (j < HDIM) row[j] = gb2[t * HDIM + j];
  __syncthreads();
  float acc = bx[j];
#pragma unroll 8
  for (int c = 0; c < HDIM; ++c) acc += row[c] * Wx[c * H3 + j];
  bf[t * H3 + j] = acc;
}

// ---- pack combined transposed fp16 weights: Wcombt[t][col(512)][k(256)] ------------------
__global__ __launch_bounds__(256) void pack_wcomb(
    const float* __restrict__ Wf32, const float* __restrict__ Wh,
    _Float16* __restrict__ Wcombt) {
  int t = blockIdx.x >> 9;
  int col = blockIdx.x & 511;
  int k = threadIdx.x;  // 0..255
  float v;
  if (col < 384) {
    if (k < 128) v = Wf32[((size_t)t * HDIM + k) * H3 + col];
    else v = (col < 256) ? Wh[(size_t)(k - 128) * H3 + col] : 0.f;
  } else {
    v = (k < 128) ? 0.f : Wh[(size_t)(k - 128) * H3 + (col - 128)];
  }
  Wcombt[((size_t)t * 512 + col) * 256 + k] = (_Float16)v;
}

// ---- pack combined bias: bcomb[t][512] ----------------------------------------------------
__global__ __launch_bounds__(512) void pack_bcomb(
    const float* __restrict__ bfb, const float* __restrict__ bh,
    float* __restrict__ bcomb) {
  int t = blockIdx.x;
  int c = threadIdx.x;
  float v;
  if (c < 256) v = bfb[t * H3 + c] + bh[c];
  else if (c < 384) v = bfb[t * H3 + c];
  else v = bh[c - 128];
  bcomb[t * 512 + c] = v;
}

// ---- static encoder + attention init ------------------------------------------------------
__global__ __launch_bounds__(128) void static_encode_attn_init(
    const float* __restrict__ dense, const int* __restrict__ sparse,
    const float* __restrict__ emb,
    const float* __restrict__ Ws, const float* __restrict__ bs,
    const float* __restrict__ Waw, const float* __restrict__ baw,
    float* __restrict__ acc, float* __restrict__ s, float* __restrict__ mx) {
  int n = blockIdx.x;
  int j = threadIdx.x;
  __shared__ float xs[G0DIM];
  if (j < G0DIM) {
    float v;
    if (j < 16) {
      v = emb[sparse[n * 2 + 0] * 16 + j];
    } else if (j < 32) {
      v = emb[VVOCAB * 16 + sparse[n * 2 + 1] * 16 + (j - 16)];
    } else {
      v = dense[n * DDIM + (j - 32)];
    }
    xs[j] = v;
  }
  __syncthreads();
  float a = bs[j];
#pragma unroll 16
  for (int k = 0; k < G0DIM; ++k) a += xs[k] * Ws[k * HDIM + j];
  a = fmaxf(a, 0.f);
  float v = tanhf(a) * Waw[j];
  __shared__ float red[2];
  int lane = j & 63, wid = j >> 6;
#pragma unroll
  for (int off = 32; off > 0; off >>= 1) v += __shfl_down(v, off, 64);
  if (lane == 0) red[wid] = v;
  __syncthreads();
  acc[(size_t)n * HDIM + j] = a;
  if (j == 0) {
    s[n] = 1.f;
    mx[n] = red[0] + red[1] + baw[0];
  }
}

// ---------------- dynamic feature gather -> fp16, 8 halves/thread -------------------------
__global__ __launch_bounds__(256) void dynx_gather_h(
    const float* __restrict__ dense_t, const int* __restrict__ sparse_t,
    const float* __restrict__ emb, _Float16* __restrict__ xout) {
  int idx = blockIdx.x * 256 + threadIdx.x;  // over N*8
  int n = idx >> 3, k8 = idx & 7;
  if (n >= NNODES) return;
  const float* src;
  if (k8 < 2)
    src = &emb[sparse_t[n * 2 + 0] * 16 + k8 * 8];
  else if (k8 < 4)
    src = &emb[VVOCAB * 16 + sparse_t[n * 2 + 1] * 16 + (k8 - 2) * 8];
  else
    src = &dense_t[n * DDIM + (k8 - 4) * 8];
  float4 f0 = *(const float4*)src;
  float4 f1 = *(const float4*)(src + 4);
  v8h v = {(_Float16)f0.x, (_Float16)f0.y, (_Float16)f0.z, (_Float16)f0.w,
           (_Float16)f1.x, (_Float16)f1.y, (_Float16)f1.z, (_Float16)f1.w};
  *(v8h*)&xout[(size_t)n * G0DIM + k8 * 8] = v;
}

// ---------------- row matmul (fp16 in/out): 64 thr, NB=8 nodes, 2 cols/thread -------------
__global__ __launch_bounds__(64) void rowmm64(
    const _Float16* __restrict__ x, const float* __restrict__ W,
    const float* __restrict__ b, _Float16* __restrict__ y) {
  const int NB = 8;
  int n0 = blockIdx.x * NB;
  int j = threadIdx.x;
  __shared__ float xT[G0DIM][12];
#pragma unroll
  for (int q = 0; q < NB; ++q) xT[j][q] = (float)x[(size_t)(n0 + q) * G0DIM + j];
  __syncthreads();
  float acc0[NB], acc1[NB];
#pragma unroll
  for (int q = 0; q < NB; ++q) { acc0[q] = 0.f; acc1[q] = 0.f; }
#pragma unroll 4
  for (int k = 0; k < G0DIM; ++k) {
    float4 a = *(const float4*)&xT[k][0];
    float4 c = *(const float4*)&xT[k][4];
    float w0 = W[(size_t)k * HDIM + j];
    float w1 = W[(size_t)k * HDIM + j + 64];
    acc0[0] += a.x * w0; acc0[1] += a.y * w0; acc0[2] += a.z * w0; acc0[3] += a.w * w0;
    acc0[4] += c.x * w0; acc0[5] += c.y * w0; acc0[6] += c.z * w0; acc0[7] += c.w * w0;
    acc1[0] += a.x * w1; acc1[1] += a.y * w1; acc1[2] += a.z * w1; acc1[3] += a.w * w1;
    acc1[4] += c.x * w1; acc1[5] += c.y * w1; acc1[6] += c.z * w1; acc1[7] += c.w * w1;
  }
  float b0 = b[j], b1 = b[j + 64];
#pragma unroll
  for (int q = 0; q < NB; ++q) {
    y[(size_t)(n0 + q) * HDIM + j] = (_Float16)fmaxf(acc0[q] + b0, 0.f);
    y[(size_t)(n0 + q) * HDIM + j + 64] = (_Float16)fmaxf(acc1[q] + b1, 0.f);
  }
}

__device__ __forceinline__ float sigmoidf_(float v) {
  return 1.f / (1.f + expf(-v));
}

// ---------------- MFMA GRU + attention: 32 nodes/block, 4 waves ---------------------------
// last!=0: fold the final softmax division in (no hout write, acc = final output).
__global__ __launch_bounds__(256) void gru_mfma(
    const _Float16* __restrict__ Xh, const _Float16* __restrict__ Hp,
    const _Float16* __restrict__ Bt, const float* __restrict__ bcomb,
    const float* __restrict__ Waw, const float* __restrict__ baw,
    _Float16* __restrict__ hout, float* __restrict__ acc,
    float* __restrict__ sden, float* __restrict__ mxv, int last) {
  const int AST = 264;
  __shared__ _Float16 A_lds[32 * AST];
  __shared__ float h_lds[32 * 132];
  __shared__ float lg[32], facs[32], ps[32], sdn[32];
  int tid = threadIdx.x;
  int w = tid >> 6, lane = tid & 63;
  int n0 = blockIdx.x * 32;

#pragma unroll
  for (int i = 0; i < 4; ++i) {
    int cid = tid + i * 256;
    int row = cid >> 5, ch = cid & 31;
    int n = n0 + row;
    v8h v = {(_Float16)0, (_Float16)0, (_Float16)0, (_Float16)0,
             (_Float16)0, (_Float16)0, (_Float16)0, (_Float16)0};
    if (n < NNODES) {
      if (ch < 16) v = *(const v8h*)&Xh[(size_t)n * HDIM + ch * 8];
      else if (Hp) v = *(const v8h*)&Hp[(size_t)n * HDIM + (ch - 16) * 8];
    }
    *(v8h*)&A_lds[row * AST + ch * 8] = v;
  }
  __syncthreads();

  int lj = lane & 15, lr = lane >> 4;
  v4f accf[2][8];
#pragma unroll
  for (int m = 0; m < 2; ++m)
#pragma unroll
    for (int f = 0; f < 8; ++f) accf[m][f] = (v4f){0.f, 0.f, 0.f, 0.f};

  for (int ks = 0; ks < 8; ++ks) {
    v8h a0 = *(const v8h*)&A_lds[lj * AST + ks * 32 + lr * 8];
    v8h a1 = *(const v8h*)&A_lds[(16 + lj) * AST + ks * 32 + lr * 8];
#pragma unroll
    for (int g = 0; g < 4; ++g)
#pragma unroll
      for (int p = 0; p < 2; ++p) {
        int col = (g * 8 + w * 2 + p) * 16 + lj;
        v8h b = *(const v8h*)&Bt[(size_t)col * 256 + ks * 32 + lr * 8];
        accf[0][g * 2 + p] =
            __builtin_amdgcn_mfma_f32_16x16x32_f16(a0, b, accf[0][g * 2 + p], 0, 0, 0);
        accf[1][g * 2 + p] =
            __builtin_amdgcn_mfma_f32_16x16x32_f16(a1, b, accf[1][g * 2 + p], 0, 0, 0);
      }
  }

#pragma unroll
  for (int p = 0; p < 2; ++p) {
    int j = (w * 2 + p) * 16 + lj;
    float br = bcomb[j], bz = bcomb[128 + j], bxn = bcomb[256 + j], bhn = bcomb[384 + j];
#pragma unroll
    for (int m = 0; m < 2; ++m)
#pragma unroll
      for (int reg = 0; reg < 4; ++reg) {
        int row = m * 16 + lr * 4 + reg;
        float r = sigmoidf_(accf[m][0 + p][reg] + br);
        float z = sigmoidf_(accf[m][2 + p][reg] + bz);
        float hp = (float)A_lds[row * AST + 128 + j];
        float nc = tanhf(accf[m][4 + p][reg] + bxn + r * (accf[m][6 + p][reg] + bhn));
        h_lds[row * 132 + j] = (1.f - z) * nc + z * hp;
      }
  }
  __syncthreads();

  float waw0 = Waw[lane], waw1 = Waw[lane + 64];
#pragma unroll
  for (int q = 0; q < 8; ++q) {
    int row = w * 8 + q;
    float v = tanhf(h_lds[row * 132 + lane]) * waw0 +
              tanhf(h_lds[row * 132 + lane + 64]) * waw1;
#pragma unroll
    for (int off = 32; off > 0; off >>= 1) v += __shfl_down(v, off, 64);
    if (lane == 0) lg[row] = v;
  }
  __syncthreads();
  if (tid < 32) {
    int n = n0 + tid;
    if (n < NNODES) {
      float l = lg[tid] + baw[0];
      float m = mxv[n];
      float mnew = fmaxf(m, l);
      float fac = expf(m - mnew);
      float pp = expf(l - mnew);
      facs[tid] = fac;
      ps[tid] = pp;
      float snew = sden[n] * fac + pp;
      sdn[tid] = snew;
      sden[n] = snew;
      mxv[n] = mnew;
    }
  }
  __syncthreads();
  if (last) {
#pragma unroll
    for (int i = 0; i < 16; ++i) {
      int idx = tid + i * 256;
      int row = idx >> 7, col = idx & 127;
      int n = n0 + row;
      if (n < NNODES) {
        float hv = h_lds[row * 132 + col];
        size_t o = (size_t)n * HDIM + col;
        acc[o] = (acc[o] * facs[row] + ps[row] * hv) / sdn[row];
      }
    }
  } else {
#pragma unroll
    for (int i = 0; i < 16; ++i) {
      int idx = tid + i * 256;
      int row = idx >> 7, col = idx & 127;
      int n = n0 + row;
      if (n < NNODES) {
        float hv = h_lds[row * 132 + col];
        size_t o = (size_t)n * HDIM + col;
        acc[o] = acc[o] * facs[row] + ps[row] * hv;
        hout[o] = (_Float16)hv;
      }
    }
  }
}

extern "C" void kernel_launch(void* const* d_in, const int* in_sizes, int n_in,
                              void* d_out, int out_size, void* d_ws, size_t ws_size,
                              hipStream_t stream) {
  const float* static_dense = (const float*)d_in[0];
  const int*   static_sparse = (const int*)d_in[1];
  const float* dyn_dense = (const float*)d_in[2];
  const int*   dyn_sparse = (const int*)d_in[3];
  const int*   edges = (const int*)d_in[4];
  const float* weights = (const float*)d_in[5];
  const float* s_emb = (const float*)d_in[6];
  const float* d_emb = (const float*)d_in[7];
  const float* Ws = (const float*)d_in[8];
  const float* bs = (const float*)d_in[9];
  const float* gW1 = (const float*)d_in[10];
  const float* gb1 = (const float*)d_in[11];
  const float* gW2 = (const float*)d_in[12];
  const float* gb2 = (const float*)d_in[13];
  const float* Wx = (const float*)d_in[14];
  const float* Wh = (const float*)d_in[15];
  const float* bx = (const float*)d_in[16];
  const float* bh = (const float*)d_in[17];
  const float* Waw = (const float*)d_in[18];
  const float* baw = (const float*)d_in[19];
  float* out = (float*)d_out;  // attention accumulator [N,128] fp32

  const size_t N = NNODES;
  char* p = (char*)d_ws;
  auto alloc = [&](size_t bytes) { char* r = p; p += (bytes + 255) & ~(size_t)255; return r; };
  float*     sden   = (float*)alloc(N * 4);
  float*     mxv    = (float*)alloc(N * 4);
  _Float16*  hA     = (_Float16*)alloc(N * HDIM * 2);
  _Float16*  hB     = (_Float16*)alloc(N * HDIM * 2);
  _Float16*  dynx   = (_Float16*)alloc(N * G0DIM * 2);
  _Float16*  m1h    = (_Float16*)alloc(N * G0DIM * 2);
  // rank (8*800000*4 = 25.6MB) aliases [h1h|Xh] (2*N*128*2 = 25.6MB):
  // rank is fully consumed by fill_csr_all BEFORE the loop's first rowmm64 write (stream order).
  char*      ralias = alloc((size_t)TSTEPS * NEDGES * 4);
  int*       rank   = (int*)ralias;
  _Float16*  h1h    = (_Float16*)ralias;
  _Float16*  Xh     = h1h + N * HDIM;
  float*     Wf32   = (float*)alloc((size_t)TSTEPS * HDIM * H3 * 4);
  _Float16*  Wcombt = (_Float16*)alloc((size_t)TSTEPS * 512 * 256 * 2);
  float*     bfb    = (float*)alloc((size_t)TSTEPS * H3 * 4);
  float*     bcomb  = (float*)alloc((size_t)TSTEPS * 512 * 4);
  int*       deg    = (int*)alloc((size_t)TSTEPS * N * 4);
  int*       offs   = (int*)alloc((size_t)TSTEPS * (N + 1) * 4);
  int*       csum   = (int*)alloc((size_t)TSTEPS * NCH * 4);
  int*       cbase  = (int*)alloc((size_t)TSTEPS * NCH * 4);
  int2*      csr    = (int2*)alloc((size_t)TSTEPS * NEDGES * 8);  // all-t CSR, 51.2MB

  const int EB = (NEDGES + 255) / 256;

  // ---- batched CSR for all timesteps: hist(+rank) -> scan -> atomic-free fill ----
  fill_zero_int<<<(TSTEPS * NNODES + 255) / 256, 256, 0, stream>>>(deg, TSTEPS * NNODES);
  hist_all<<<dim3(EB, TSTEPS), 256, 0, stream>>>(edges, deg, rank);
  scan_k1<<<TSTEPS * NCH, 256, 0, stream>>>(deg, csum);
  scan_k2<<<TSTEPS, 128, 0, stream>>>(csum, cbase, offs);
  scan_k3<<<TSTEPS * NCH, 512, 0, stream>>>(deg, cbase, offs);
  fill_csr_all<<<dim3(EB, TSTEPS), 256, 0, stream>>>(edges, weights, rank, offs, csr);

  // ---- weight/bias preprocessing ----
  fuse_w<<<TSTEPS * HDIM, H3, 0, stream>>>(gW2, Wx, Wf32);
  fuse_b<<<TSTEPS, H3, 0, stream>>>(gb2, Wx, bx, bfb);
  pack_wcomb<<<TSTEPS * 512, 256, 0, stream>>>(Wf32, Wh, Wcombt);
  pack_bcomb<<<TSTEPS, 512, 0, stream>>>(bfb, bh, bcomb);

  static_encode_attn_init<<<NNODES, 128, 0, stream>>>(
      static_dense, static_sparse, s_emb, Ws, bs, Waw, baw, out, sden, mxv);

  const int GRUB = (NNODES + 31) / 32;
  for (int t = 0; t < TSTEPS; ++t) {
    const int* off_t = offs + (size_t)t * (N + 1);
    const int2* csr_t = csr + (size_t)t * NEDGES;
    _Float16* hcur = (t & 1) ? hB : hA;
    const _Float16* hprev = (t == 0) ? nullptr : ((t & 1) ? hA : hB);

    dynx_gather_h<<<(NNODES * 8 + 255) / 256, 256, 0, stream>>>(
        dyn_dense + (size_t)t * N * DDIM, dyn_sparse + (size_t)t * N * 2, d_emb, dynx);

    gather_agg_h<G0DIM><<<(NNODES + 31) / 32, 256, 0, stream>>>(off_t, csr_t, dynx, m1h);

    rowmm64<<<NNODES / 8, 64, 0, stream>>>(
        m1h, gW1 + (size_t)t * G0DIM * HDIM, gb1 + (size_t)t * HDIM, h1h);

    gather_agg_h<HDIM><<<(NNODES + 15) / 16, 256, 0, stream>>>(off_t, csr_t, h1h, Xh);

    gru_mfma<<<GRUB, 256, 0, stream>>>(
        Xh, hprev, Wcombt + (size_t)t * 512 * 256, bcomb + t * 512,
        Waw, baw, hcur, out, sden, mxv, t == TSTEPS - 1 ? 1 : 0);
  }
}